// Round 2
// baseline (1023.383 us; speedup 1.0000x reference)
//
#include <hip/hip_runtime.h>
#include <hip/hip_bf16.h>

static constexpr float kLog2 = 0.6931471805599453f;

__device__ __forceinline__ float sspf(float x) {
    return fmaxf(x, 0.0f) + __logf(1.0f + __expf(-fabsf(x))) - kLog2;
}

typedef __attribute__((ext_vector_type(8))) _Float16 half8;
typedef __attribute__((ext_vector_type(4))) _Float16 half4v;
typedef __attribute__((ext_vector_type(4))) float float4v;

// ---------------- dense GEMMs (f16 MFMA 16x16x32, whole K in LDS) ----------
// PERM: write C columns in the gather-friendly permuted layout
//   phi(n) = (n>>6)*64 + ((n>>2)&3)*16 + ((n>>4)&3)*4 + (n&3)
// so a gather lane (q) reads 32B contiguous per row half.
template <bool PERM, bool ACT, typename OUT>
__device__ __forceinline__ void gemm_mfma_body(const float* __restrict__ A,
                                               const float* __restrict__ B,
                                               const float* __restrict__ bias,
                                               OUT* __restrict__ C, int M,
                                               int blockid) {
    constexpr int LDH = 136;
    __shared__ _Float16 Als[64 * LDH];
    __shared__ _Float16 Bls[128 * LDH];
    const int tid = threadIdx.x;
    const int rowbase = blockid * 64;
#pragma unroll
    for (int j = 0; j < 8; ++j) {
        int idx = j * 256 + tid;
        int r = idx >> 5, c4 = (idx & 31) << 2;
        int rg = rowbase + r;
        rg = rg < M ? rg : (M - 1);
        float4 v = *(const float4*)(A + (size_t)rg * 128 + c4);
        half4v hv = {(_Float16)v.x, (_Float16)v.y, (_Float16)v.z, (_Float16)v.w};
        *(half4v*)&Als[r * LDH + c4] = hv;
    }
#pragma unroll
    for (int j = 0; j < 16; ++j) {
        int idx = j * 256 + tid;
        int r = idx >> 5, c4 = (idx & 31) << 2;
        float4 v = *(const float4*)(B + (size_t)r * 128 + c4);
        half4v hv = {(_Float16)v.x, (_Float16)v.y, (_Float16)v.z, (_Float16)v.w};
        *(half4v*)&Bls[r * LDH + c4] = hv;
    }
    __syncthreads();

    const int wave = tid >> 6, lane = tid & 63;
    const int l15 = lane & 15, q = lane >> 4;
    float4v acc[8];
#pragma unroll
    for (int nt = 0; nt < 8; ++nt) acc[nt] = (float4v){0.f, 0.f, 0.f, 0.f};
    const int am = wave * 16 + l15;
#pragma unroll
    for (int kk = 0; kk < 4; ++kk) {
        half8 af = *(const half8*)&Als[am * LDH + kk * 32 + q * 8];
#pragma unroll
        for (int nt = 0; nt < 8; ++nt) {
            half8 bfv = *(const half8*)&Bls[(nt * 16 + l15) * LDH + kk * 32 + q * 8];
            acc[nt] = __builtin_amdgcn_mfma_f32_16x16x32_f16(af, bfv, acc[nt], 0, 0, 0);
        }
    }
#pragma unroll
    for (int nt = 0; nt < 8; ++nt) {
        int n = nt * 16 + l15;
        float bv = bias[n];
        int pn = n;
        if (PERM) {
            pn = ((n >> 6) << 6) + (((n >> 2) & 3) << 4) + (((n >> 4) & 3) << 2) +
                 (n & 3);
        }
#pragma unroll
        for (int r = 0; r < 4; ++r) {
            int m = rowbase + wave * 16 + q * 4 + r;
            if (m < M) {
                float v = acc[nt][r] + bv;
                if (ACT) v = sspf(v);
                C[(size_t)m * 128 + pn] = (OUT)v;
            }
        }
    }
}

template <bool PERM>
__global__ __launch_bounds__(256) void gemm_in_count_kernel(
    const float* __restrict__ A, const float* __restrict__ B,
    const float* __restrict__ bias, _Float16* __restrict__ C, int M,
    const int* __restrict__ idx_i, int* __restrict__ counts, int P,
    int gemm_blocks) {
    if ((int)blockIdx.x < gemm_blocks) {
        gemm_mfma_body<PERM, false, _Float16>(A, B, bias, C, M, blockIdx.x);
    } else {
        const int nthr = (gridDim.x - gemm_blocks) * 256;
        for (int p = (blockIdx.x - gemm_blocks) * 256 + threadIdx.x; p < P;
             p += nthr)
            atomicAdd(&counts[idx_i[p]], 1);
    }
}

__global__ __launch_bounds__(256) void gemm_out_kernel(
    const float* __restrict__ A, const float* __restrict__ B,
    const float* __restrict__ bias, float* __restrict__ C, int M) {
    gemm_mfma_body<false, true, float>(A, B, bias, C, M, blockIdx.x);
}

// ---- one-kernel segment allocation: block scan + global bump (order-free) ----
__global__ __launch_bounds__(256) void alloc_starts_kernel(
    const int* __restrict__ counts, int* __restrict__ starts,
    int* __restrict__ cursor, int* __restrict__ gtot, int N) {
    __shared__ int s[256];
    __shared__ int base;
    const int t = threadIdx.x, g = blockIdx.x * 256 + t;
    const int c = g < N ? counts[g] : 0;
    s[t] = c;
    __syncthreads();
    for (int o = 1; o < 256; o <<= 1) {
        int v = t >= o ? s[t - o] : 0;
        __syncthreads();
        s[t] += v;
        __syncthreads();
    }
    if (t == 255) base = atomicAdd(gtot, s[255]);
    __syncthreads();
    const int excl = base + s[t] - c;
    if (g < N) {
        starts[g] = excl;
        cursor[g] = excl;
    }
}

// ============================================================================
// NEW PATH: dense filter precompute (fill+filter fused) + lean gather.
// wij[pos, :] holds f16 of ssp(z)*rcut in the lane-permuted layout
//   within each 64-feature block: [q*16 + t_local*4 + r]
// so both producer store and consumer load are 16B-contiguous per lane.
// ============================================================================

// FT tiles of 16 features each, starting at feature fb. One wave = 16 edges.
template <int FT, bool ASSIGN>
__global__ __launch_bounds__(256) void filter_fill_kernel(
    const float* __restrict__ f_ij, const int* __restrict__ idx_i,
    const int* __restrict__ idx_j, const float* __restrict__ rcut,
    const float* __restrict__ Wf, const float* __restrict__ bfil,
    int* __restrict__ cursor, int* __restrict__ meta, int* __restrict__ posof,
    _Float16* __restrict__ wij, int P, int stride, int fb) {
    const int lane = threadIdx.x & 63;
    const int gw = (blockIdx.x * 256 + threadIdx.x) >> 6;
    const int pb = gw * 16;
    if (pb >= P) return;
    const int l15 = lane & 15, q = lane >> 4;

    // A-fragments: W_filter rows (feature fb + t*16 + l15), bias at k=20.
    half8 wfr[FT];
#pragma unroll
    for (int t = 0; t < FT; ++t) {
        const int n = fb + t * 16 + l15;
        const float* wr = Wf + (size_t)n * 20;
        float v[8];
#pragma unroll
        for (int j = 0; j < 8; ++j) {
            int k = q * 8 + j;
            v[j] = (k < 20) ? wr[k] : ((k == 20) ? bfil[n] : 0.0f);
        }
        wfr[t] = (half8){(_Float16)v[0], (_Float16)v[1], (_Float16)v[2],
                         (_Float16)v[3], (_Float16)v[4], (_Float16)v[5],
                         (_Float16)v[6], (_Float16)v[7]};
    }

    const int p = pb + l15;
    const bool pv = p < P;
    const int pc = pv ? p : (P - 1);
    const float rc = rcut[pc];

    int pos;
    if (ASSIGN) {
        int pos0 = 0;
        if (q == 0 && pv) {
            pos0 = atomicAdd(&cursor[idx_i[p]], 1);
            meta[pos0] = idx_j[p] << 7;
            posof[p] = pos0;
        }
        pos = __shfl(pos0, l15, 64);
    } else {
        pos = posof[pc];
    }

    // B-fragment from f32 f_ij rows (k = q*8 + j, bias-mult 1.0 at k=20).
    const float* fp = f_ij + (size_t)pc * 20;
    float b0 = 0.f, b1 = 0.f, b2 = 0.f, b3 = 0.f;
    float b4 = 0.f, b5 = 0.f, b6 = 0.f, b7 = 0.f;
    if (q <= 2) {
        float4 a = *(const float4*)(fp + q * 8);
        b0 = a.x; b1 = a.y; b2 = a.z; b3 = a.w;
    }
    if (q <= 1) {
        float4 bb = *(const float4*)(fp + q * 8 + 4);
        b4 = bb.x; b5 = bb.y; b6 = bb.z; b7 = bb.w;
    }
    if (q == 2) b4 = 1.0f;
    const half8 bfc = (half8){(_Float16)b0, (_Float16)b1, (_Float16)b2,
                              (_Float16)b3, (_Float16)b4, (_Float16)b5,
                              (_Float16)b6, (_Float16)b7};

    const float4v zero = {0.f, 0.f, 0.f, 0.f};
    const float rcln2 = rc * 0.69314718f;
    _Float16 wst[FT * 4];
#pragma unroll
    for (int t = 0; t < FT; ++t) {
        float4v d = __builtin_amdgcn_mfma_f32_16x16x32_f16(wfr[t], bfc, zero, 0, 0, 0);
#pragma unroll
        for (int r = 0; r < 4; ++r) {
            float x = d[r];
            float mx = fmaxf(x, 0.0f);
            float e2 = exp2f(-fabsf(x) * 1.44269504f);
            float lg = log2f(1.0f + e2);
            // w = (mx + lg*ln2 - ln2) * rc
            float w = fmaf(lg, rcln2, fmaf(mx, rc, -rcln2));
            wst[t * 4 + r] = (_Float16)w;
        }
    }
    if (pv) {
        _Float16* wb = wij + (size_t)pos * stride;
        if (FT == 8) {
            *(half8*)(wb + q * 16) = *(half8*)&wst[0];
            *(half8*)(wb + q * 16 + 8) = *(half8*)&wst[8];
            *(half8*)(wb + 64 + q * 16) = *(half8*)&wst[16];
            *(half8*)(wb + 64 + q * 16 + 8) = *(half8*)&wst[24];
        } else if (FT == 4) {
            *(half8*)(wb + q * 16) = *(half8*)&wst[0];
            *(half8*)(wb + q * 16 + 8) = *(half8*)&wst[8];
        } else {
            *(half8*)(wb + q * 8) = *(half8*)&wst[0];
        }
    }
}

// ---- lean gather: per chunk only {meta dword, coalesced wij, 1-line h rows,
//      16 mixed-precision FMAs}. GT tiles (GT*16 features) per wave. ----
template <int GT>
__global__ __launch_bounds__(256) void gather_lean_kernel(
    const _Float16* __restrict__ wij, const int* __restrict__ meta,
    const _Float16* __restrict__ h16, const int* __restrict__ starts,
    const int* __restrict__ counts, float* __restrict__ agg, int units,
    int stride, int fb_fixed, int split) {
    constexpr int NH = GT / 2;  // half8s per operand per lane
    const int lane = threadIdx.x & 63;
    const int gwave = (blockIdx.x * 256 + threadIdx.x) >> 6;
    const int nwaves = (gridDim.x * 256) >> 6;
    const int l15 = lane & 15, q = lane >> 4;
    const half8 hzero = {};

    for (int u = gwave; u < units; u += nwaves) {
        int i, fbw, woff;
        if (split) {
            i = u >> 1;
            fbw = (u & 1) << 6;
            woff = fbw + (q << 4);
        } else {
            i = u;
            fbw = fb_fixed;
            woff = q * (GT * 4);
        }
        const int hoff = ((fbw >> 6) << 6) + (q << 4) + (((fbw >> 4) & 3) << 2);
        const int s = __builtin_amdgcn_readfirstlane(starts[i]);
        const int cnt = __builtin_amdgcn_readfirstlane(counts[i]);
        const int e = s + cnt;
        float4v acc[GT];
#pragma unroll
        for (int t = 0; t < GT; ++t) acc[t] = (float4v){0.f, 0.f, 0.f, 0.f};

        if (cnt > 0) {
            int pos_c = min(s + l15, e - 1);
            bool vl_c = (s + l15) < e;
            int jb_c = meta[pos_c];
            half8 wv_c[NH], hv_c[NH];
            {
                const _Float16* wp = wij + (size_t)pos_c * stride + woff;
                const _Float16* hp = h16 + jb_c + hoff;
#pragma unroll
                for (int h = 0; h < NH; ++h) {
                    wv_c[h] = *(const half8*)(wp + h * 8);
                    hv_c[h] = *(const half8*)(hp + h * 8);
                }
            }
            int pos_n = pos_c, jb_n = jb_c;
            bool vl_n = false;
            if (s + 16 < e) {
                pos_n = min(s + 16 + l15, e - 1);
                jb_n = meta[pos_n];
                vl_n = (s + 16 + l15) < e;
            }
            for (int c = s; c < e; c += 16) {
                half8 wv_n[NH], hv_n[NH];
                if (c + 16 < e) {  // stage next chunk payload
                    const _Float16* wp = wij + (size_t)pos_n * stride + woff;
                    const _Float16* hp = h16 + jb_n + hoff;
#pragma unroll
                    for (int h = 0; h < NH; ++h) {
                        wv_n[h] = *(const half8*)(wp + h * 8);
                        hv_n[h] = *(const half8*)(hp + h * 8);
                    }
                }
                int pos_n2 = pos_n, jb_n2 = jb_n;
                bool vl_n2 = vl_n;
                if (c + 32 < e) {  // meta two chunks ahead
                    pos_n2 = min(c + 32 + l15, e - 1);
                    jb_n2 = meta[pos_n2];
                    vl_n2 = (c + 32 + l15) < e;
                }
                if (!vl_c) {
#pragma unroll
                    for (int h = 0; h < NH; ++h) wv_c[h] = hzero;
                }
#pragma unroll
                for (int h = 0; h < NH; ++h) {
#pragma unroll
                    for (int j = 0; j < 8; ++j) {
                        int t = (h * 8 + j) >> 2, r = j & 3;
                        acc[t][r] = fmaf((float)wv_c[h][j], (float)hv_c[h][j],
                                         acc[t][r]);
                    }
                }
#pragma unroll
                for (int h = 0; h < NH; ++h) {
                    wv_c[h] = wv_n[h];
                    hv_c[h] = hv_n[h];
                }
                vl_c = vl_n; vl_n = vl_n2;
                pos_n = pos_n2; jb_n = jb_n2;
            }
        }
        // reduce across the 16-edge (l15) dimension
#pragma unroll
        for (int m = 1; m <= 8; m <<= 1)
#pragma unroll
            for (int t = 0; t < GT; ++t)
#pragma unroll
                for (int r = 0; r < 4; ++r)
                    acc[t][r] += __shfl_xor(acc[t][r], m, 64);
        if (l15 == 0) {
#pragma unroll
            for (int t = 0; t < GT; ++t) {
                float4 o = {acc[t][0], acc[t][1], acc[t][2], acc[t][3]};
                *(float4*)(agg + (size_t)i * 128 + fbw + t * 16 + q * 4) = o;
            }
        }
    }
}

// ============================================================================
// OLD PATH (fallback when workspace is too small for wij): unchanged R1 code.
// ============================================================================
template <bool EF>
__global__ __launch_bounds__(256) void fill_kernel(
    const int* __restrict__ idx_i, const int* __restrict__ idx_j,
    const float* __restrict__ rcut, const float* __restrict__ f_ij,
    int* __restrict__ cursor, _Float16* __restrict__ ef,
    int2* __restrict__ meta, int* __restrict__ pidx, int P) {
    int p = blockIdx.x * 256 + threadIdx.x;
    if (p >= P) return;
    const int i = idx_i[p];
    const int pos = atomicAdd(&cursor[i], 1);
    meta[pos] = make_int2(idx_j[p] << 7, __float_as_int(rcut[p]));
    if (EF) {
        const float* fr = f_ij + (size_t)p * 20;
        _Float16 hb[24];
#pragma unroll
        for (int r = 0; r < 20; r += 4) {
            float4 v = *(const float4*)(fr + r);
            hb[r] = (_Float16)v.x; hb[r + 1] = (_Float16)v.y;
            hb[r + 2] = (_Float16)v.z; hb[r + 3] = (_Float16)v.w;
        }
        hb[20] = (_Float16)1.0f; hb[21] = (_Float16)0.0f;
        hb[22] = (_Float16)0.0f; hb[23] = (_Float16)0.0f;
        _Float16* dst = ef + (size_t)pos * 24;
        *(half8*)dst = *(half8*)hb;
        *(half8*)(dst + 8) = *(half8*)(hb + 8);
        *(half8*)(dst + 16) = *(half8*)(hb + 16);
    } else {
        pidx[pos] = p;
    }
}

template <bool EF>
__global__ __launch_bounds__(256, 4) void gather_mfma_kernel(
    const _Float16* __restrict__ ef, const int2* __restrict__ meta,
    const int* __restrict__ pidx, const float* __restrict__ f_ij,
    const float* __restrict__ Wf, const float* __restrict__ bf,
    const _Float16* __restrict__ h16, const int* __restrict__ starts,
    const int* __restrict__ counts, float* __restrict__ agg, int N) {
    const int lane = threadIdx.x & 63;
    const int gwave = (blockIdx.x * 256 + threadIdx.x) >> 6;
    const int nwaves = (gridDim.x * 256) >> 6;
    const int l15 = lane & 15, q = lane >> 4;
    const int fh = gwave & 1;
    const int fbase = fh * 64;

    half8 wfr[4];
#pragma unroll
    for (int t = 0; t < 4; ++t) {
        const int n = fbase + t * 16 + l15;
        const float* wr = Wf + (size_t)n * 20;
        float v[8];
#pragma unroll
        for (int j = 0; j < 8; ++j) {
            int k = q * 8 + j;
            v[j] = (k < 20) ? wr[k] : ((k == 20) ? bf[n] : 0.0f);
        }
        wfr[t] = (half8){(_Float16)v[0], (_Float16)v[1], (_Float16)v[2],
                         (_Float16)v[3], (_Float16)v[4], (_Float16)v[5],
                         (_Float16)v[6], (_Float16)v[7]};
    }
    const float4v zero = {0.f, 0.f, 0.f, 0.f};
    const _Float16* hbase = h16 + fbase + q * 4;

    for (int u = gwave; u < 2 * N; u += nwaves) {
        const int i = u >> 1;
        const int s = __builtin_amdgcn_readfirstlane(starts[i]);
        const int cnt = __builtin_amdgcn_readfirstlane(counts[i]);
        const int e = s + cnt;
        float4v acc[4];
#pragma unroll
        for (int t = 0; t < 4; ++t) acc[t] = zero;

        if (cnt > 0) {
            int pos0 = min(s + l15, e - 1);
            int2 mt_c = meta[pos0];
            half8 bf_c = {};
            int p_c = 0;
            if (EF) {
                if (q < 3) bf_c = *(const half8*)(ef + (size_t)pos0 * 24 + q * 8);
            } else {
                p_c = pidx[pos0];
            }
            int2 mt_n = mt_c;
            half8 bf_n = bf_c;
            int p_n = p_c;
            if (s + 16 < e) {
                int pos1 = min(s + 16 + l15, e - 1);
                mt_n = meta[pos1];
                if (EF) {
                    if (q < 3) bf_n = *(const half8*)(ef + (size_t)pos1 * 24 + q * 8);
                } else {
                    p_n = pidx[pos1];
                }
            }
            half4v hv_c[4];
            {
                const _Float16* hp = hbase + mt_c.x;
#pragma unroll
                for (int t = 0; t < 4; ++t) hv_c[t] = *(const half4v*)(hp + t * 16);
            }

            for (int c = s; c < e; c += 16) {
                half4v hv_n[4];
                if (c + 16 < e) {
                    const _Float16* hp = hbase + mt_n.x;
#pragma unroll
                    for (int t = 0; t < 4; ++t) hv_n[t] = *(const half4v*)(hp + t * 16);
                }
                int2 mt_n2 = mt_n;
                half8 bf_n2 = bf_n;
                int p_n2 = p_n;
                if (c + 32 < e) {
                    int pos2 = min(c + 32 + l15, e - 1);
                    mt_n2 = meta[pos2];
                    if (EF) {
                        if (q < 3) bf_n2 = *(const half8*)(ef + (size_t)pos2 * 24 + q * 8);
                    } else {
                        p_n2 = pidx[pos2];
                    }
                }
                if (!EF) {
                    const float* fp = f_ij + (size_t)p_c * 20;
                    float b0 = 0.f, b1 = 0.f, b2 = 0.f, b3 = 0.f;
                    float b4 = 0.f, b5 = 0.f, b6 = 0.f, b7 = 0.f;
                    if (q <= 2) {
                        float4 a = *(const float4*)(fp + q * 8);
                        b0 = a.x; b1 = a.y; b2 = a.z; b3 = a.w;
                    }
                    if (q <= 1) {
                        float4 bb = *(const float4*)(fp + q * 8 + 4);
                        b4 = bb.x; b5 = bb.y; b6 = bb.z; b7 = bb.w;
                    }
                    if (q == 2) b4 = 1.0f;
                    bf_c = (half8){(_Float16)b0, (_Float16)b1, (_Float16)b2,
                                   (_Float16)b3, (_Float16)b4, (_Float16)b5,
                                   (_Float16)b6, (_Float16)b7};
                }
                const int jb = mt_c.x;
                (void)jb;
                const float rc = (c + l15 < e) ? __int_as_float(mt_c.y) : 0.0f;
#pragma unroll
                for (int t = 0; t < 4; ++t) {
                    float4v d = __builtin_amdgcn_mfma_f32_16x16x32_f16(
                        wfr[t], bf_c, zero, 0, 0, 0);
#pragma unroll
                    for (int r = 0; r < 4; ++r) {
                        float w = sspf(d[r]) * rc;
                        acc[t][r] = fmaf(w, (float)hv_c[t][r], acc[t][r]);
                    }
                }
                mt_c = mt_n; mt_n = mt_n2;
                bf_c = bf_n; bf_n = bf_n2;
                p_c = p_n;   p_n = p_n2;
#pragma unroll
                for (int t = 0; t < 4; ++t) hv_c[t] = hv_n[t];
            }
        }
#pragma unroll
        for (int m = 1; m <= 8; m <<= 1)
#pragma unroll
            for (int t = 0; t < 4; ++t)
#pragma unroll
                for (int r = 0; r < 4; ++r)
                    acc[t][r] += __shfl_xor(acc[t][r], m, 64);
        if (l15 == 0) {
#pragma unroll
            for (int t = 0; t < 4; ++t) {
                float4 o = {acc[t][0], acc[t][1], acc[t][2], acc[t][3]};
                *(float4*)(agg + (size_t)i * 128 + fbase + t * 16 + q * 4) = o;
            }
        }
    }
}

extern "C" void kernel_launch(void* const* d_in, const int* in_sizes, int n_in,
                              void* d_out, int out_size, void* d_ws, size_t ws_size,
                              hipStream_t stream) {
    const float* x     = (const float*)d_in[0];
    const float* f_ij  = (const float*)d_in[1];
    const int*   idx_i = (const int*)d_in[2];
    const int*   idx_j = (const int*)d_in[3];
    const float* rcut  = (const float*)d_in[4];
    const float* W_in  = (const float*)d_in[5];
    const float* b_in  = (const float*)d_in[6];
    const float* W_f   = (const float*)d_in[7];
    const float* b_f   = (const float*)d_in[8];
    const float* W_out = (const float*)d_in[9];
    const float* b_out = (const float*)d_in[10];

    const int N = in_sizes[0] / 128;  // 50000
    const int P = in_sizes[2];        // 1600000

    const int mblocks = (N + 63) / 64;
    const int cblocks = 768;
    const int NB = (N + 255) / 256;
    float* agg = (float*)d_out;

    auto pad16 = [](size_t b) { return (b + 15) & ~(size_t)15; };

    // ---- new-path workspace estimate ----
    size_t base_new = pad16((size_t)N * 4 + 16) + pad16((size_t)N * 4) +
                      pad16((size_t)N * 4) + pad16((size_t)N * 128 * 2) +
                      pad16((size_t)P * 4) + pad16((size_t)P * 4);
    auto wij_bytes = [&](int stride) { return pad16((size_t)P * stride * 2 + 64); };

    int mode;  // 0=full, 1=half, 2=quarter, 3=old
    if (base_new + wij_bytes(128) <= ws_size) mode = 0;
    else if (base_new + wij_bytes(64) <= ws_size) mode = 1;
    else if (base_new + wij_bytes(32) <= ws_size) mode = 2;
    else mode = 3;

    char* ws = (char*)d_ws;
    size_t off = 0;
    auto alloc = [&](size_t bytes) {
        void* ptr = ws + off;
        off += (bytes + 15) & ~(size_t)15;
        return ptr;
    };

    if (mode != 3) {
        int* counts  = (int*)alloc((size_t)N * 4 + 16);
        int* gtot    = counts + N;
        int* starts  = (int*)alloc((size_t)N * 4);
        int* cursor  = (int*)alloc((size_t)N * 4);
        _Float16* h16 = (_Float16*)alloc((size_t)N * 128 * 2);
        int* meta    = (int*)alloc((size_t)P * 4);
        int* posof   = (int*)alloc((size_t)P * 4);
        const int stride = (mode == 0) ? 128 : (mode == 1 ? 64 : 32);
        _Float16* wij = (_Float16*)alloc((size_t)P * stride * 2 + 64);

        hipMemsetAsync(counts, 0, (size_t)N * 4 + 16, stream);
        gemm_in_count_kernel<true><<<mblocks + cblocks, 256, 0, stream>>>(
            x, W_in, b_in, h16, N, idx_i, counts, P, mblocks);
        alloc_starts_kernel<<<NB, 256, 0, stream>>>(counts, starts, cursor, gtot, N);

        const int fblocks = (P + 63) / 64;
        if (mode == 0) {
            filter_fill_kernel<8, true><<<fblocks, 256, 0, stream>>>(
                f_ij, idx_i, idx_j, rcut, W_f, b_f, cursor, meta, posof, wij, P,
                128, 0);
            gather_lean_kernel<4><<<4096, 256, 0, stream>>>(
                wij, meta, h16, starts, counts, agg, 2 * N, 128, 0, 1);
        } else if (mode == 1) {
            filter_fill_kernel<4, true><<<fblocks, 256, 0, stream>>>(
                f_ij, idx_i, idx_j, rcut, W_f, b_f, cursor, meta, posof, wij, P,
                64, 0);
            gather_lean_kernel<4><<<4096, 256, 0, stream>>>(
                wij, meta, h16, starts, counts, agg, N, 64, 0, 0);
            filter_fill_kernel<4, false><<<fblocks, 256, 0, stream>>>(
                f_ij, idx_i, idx_j, rcut, W_f, b_f, cursor, meta, posof, wij, P,
                64, 64);
            gather_lean_kernel<4><<<4096, 256, 0, stream>>>(
                wij, meta, h16, starts, counts, agg, N, 64, 64, 0);
        } else {
            filter_fill_kernel<2, true><<<fblocks, 256, 0, stream>>>(
                f_ij, idx_i, idx_j, rcut, W_f, b_f, cursor, meta, posof, wij, P,
                32, 0);
            gather_lean_kernel<2><<<4096, 256, 0, stream>>>(
                wij, meta, h16, starts, counts, agg, N, 32, 0, 0);
            filter_fill_kernel<2, false><<<fblocks, 256, 0, stream>>>(
                f_ij, idx_i, idx_j, rcut, W_f, b_f, cursor, meta, posof, wij, P,
                32, 32);
            gather_lean_kernel<2><<<4096, 256, 0, stream>>>(
                wij, meta, h16, starts, counts, agg, N, 32, 32, 0);
            filter_fill_kernel<2, false><<<fblocks, 256, 0, stream>>>(
                f_ij, idx_i, idx_j, rcut, W_f, b_f, cursor, meta, posof, wij, P,
                32, 64);
            gather_lean_kernel<2><<<4096, 256, 0, stream>>>(
                wij, meta, h16, starts, counts, agg, N, 32, 64, 0);
            filter_fill_kernel<2, false><<<fblocks, 256, 0, stream>>>(
                f_ij, idx_i, idx_j, rcut, W_f, b_f, cursor, meta, posof, wij, P,
                32, 96);
            gather_lean_kernel<2><<<4096, 256, 0, stream>>>(
                wij, meta, h16, starts, counts, agg, N, 32, 96, 0);
        }
        gemm_out_kernel<<<mblocks, 256, 0, stream>>>(agg, W_out, b_out,
                                                     (float*)d_out, N);
        return;
    }

    // ---- old path ----
    int* counts  = (int*)alloc((size_t)N * 4 + 16);
    int* gtot    = counts + N;
    int* starts  = (int*)alloc((size_t)N * 4);
    int* cursor  = (int*)alloc((size_t)N * 4);
    _Float16* h16 = (_Float16*)alloc((size_t)N * 128 * 2);
    int2* meta2  = (int2*)alloc((size_t)P * 8);
    size_t base_need = off;
    const bool use_ef = (base_need + (size_t)P * 24 * 2 + 64) <= ws_size;
    _Float16* ef = nullptr;
    int* pidx = nullptr;
    if (use_ef) ef = (_Float16*)alloc((size_t)P * 24 * 2 + 64);
    else        pidx = (int*)alloc((size_t)P * 4);

    hipMemsetAsync(counts, 0, (size_t)N * 4 + 16, stream);
    gemm_in_count_kernel<false><<<mblocks + cblocks, 256, 0, stream>>>(
        x, W_in, b_in, h16, N, idx_i, counts, P, mblocks);
    alloc_starts_kernel<<<NB, 256, 0, stream>>>(counts, starts, cursor, gtot, N);
    if (use_ef) {
        fill_kernel<true><<<(P + 255) / 256, 256, 0, stream>>>(
            idx_i, idx_j, rcut, f_ij, cursor, ef, meta2, pidx, P);
        gather_mfma_kernel<true><<<4096, 256, 0, stream>>>(
            ef, meta2, pidx, f_ij, W_f, b_f, h16, starts, counts, agg, N);
    } else {
        fill_kernel<false><<<(P + 255) / 256, 256, 0, stream>>>(
            idx_i, idx_j, rcut, f_ij, cursor, ef, meta2, pidx, P);
        gather_mfma_kernel<false><<<4096, 256, 0, stream>>>(
            ef, meta2, pidx, f_ij, W_f, b_f, h16, starts, counts, agg, N);
    }
    gemm_out_kernel<<<mblocks, 256, 0, stream>>>(agg, W_out, b_out, (float*)d_out, N);
}

// Round 4
// 695.189 us; speedup vs baseline: 1.4721x; 1.4721x over previous
//
#include <hip/hip_runtime.h>
#include <hip/hip_bf16.h>

static constexpr float kLog2 = 0.6931471805599453f;

__device__ __forceinline__ float sspf(float x) {
    return fmaxf(x, 0.0f) + __logf(1.0f + __expf(-fabsf(x))) - kLog2;
}

typedef __attribute__((ext_vector_type(8))) _Float16 half8;
typedef __attribute__((ext_vector_type(4))) _Float16 half4v;
typedef __attribute__((ext_vector_type(4))) float float4v;

// Feature permutation for h16 rows (producer: gemm_in, consumer: gather).
// p(f) = f6 f5 f3 f2 f4 f1 f0  (bit shuffle, bijective on [0,128)).
// Gather lane (q = lane>>4) then reads its 16 needed features for tile t as
// hv[t>>1][(t&1)*4 + r] from half8 loads at element offset (t>>1)*32 + q*8:
// the 4 q-lanes of one edge row cover one aligned 64B line per instruction.
__device__ __forceinline__ int hperm(int n) {
    return ((n >> 6) << 6) | (((n >> 5) & 1) << 5) | (((n >> 2) & 3) << 3) |
           (((n >> 4) & 1) << 2) | (n & 3);
}

// ---------------- dense GEMMs (f16 MFMA 16x16x32, whole K in LDS) ----------
template <bool PERM, bool ACT, typename OUT>
__device__ __forceinline__ void gemm_mfma_body(const float* __restrict__ A,
                                               const float* __restrict__ B,
                                               const float* __restrict__ bias,
                                               OUT* __restrict__ C, int M,
                                               int blockid) {
    constexpr int LDH = 136;
    __shared__ _Float16 Als[64 * LDH];
    __shared__ _Float16 Bls[128 * LDH];
    const int tid = threadIdx.x;
    const int rowbase = blockid * 64;
#pragma unroll
    for (int j = 0; j < 8; ++j) {
        int idx = j * 256 + tid;
        int r = idx >> 5, c4 = (idx & 31) << 2;
        int rg = rowbase + r;
        rg = rg < M ? rg : (M - 1);
        float4 v = *(const float4*)(A + (size_t)rg * 128 + c4);
        half4v hv = {(_Float16)v.x, (_Float16)v.y, (_Float16)v.z, (_Float16)v.w};
        *(half4v*)&Als[r * LDH + c4] = hv;
    }
#pragma unroll
    for (int j = 0; j < 16; ++j) {
        int idx = j * 256 + tid;
        int r = idx >> 5, c4 = (idx & 31) << 2;
        float4 v = *(const float4*)(B + (size_t)r * 128 + c4);
        half4v hv = {(_Float16)v.x, (_Float16)v.y, (_Float16)v.z, (_Float16)v.w};
        *(half4v*)&Bls[r * LDH + c4] = hv;
    }
    __syncthreads();

    const int wave = tid >> 6, lane = tid & 63;
    const int l15 = lane & 15, q = lane >> 4;
    float4v acc[8];
#pragma unroll
    for (int nt = 0; nt < 8; ++nt) acc[nt] = (float4v){0.f, 0.f, 0.f, 0.f};
    const int am = wave * 16 + l15;
#pragma unroll
    for (int kk = 0; kk < 4; ++kk) {
        half8 af = *(const half8*)&Als[am * LDH + kk * 32 + q * 8];
#pragma unroll
        for (int nt = 0; nt < 8; ++nt) {
            half8 bfv = *(const half8*)&Bls[(nt * 16 + l15) * LDH + kk * 32 + q * 8];
            acc[nt] = __builtin_amdgcn_mfma_f32_16x16x32_f16(af, bfv, acc[nt], 0, 0, 0);
        }
    }
#pragma unroll
    for (int nt = 0; nt < 8; ++nt) {
        int n = nt * 16 + l15;
        float bv = bias[n];
        const int pn = PERM ? hperm(n) : n;
#pragma unroll
        for (int r = 0; r < 4; ++r) {
            int m = rowbase + wave * 16 + q * 4 + r;
            if (m < M) {
                float v = acc[nt][r] + bv;
                if (ACT) v = sspf(v);
                C[(size_t)m * 128 + pn] = (OUT)v;
            }
        }
    }
}

__global__ __launch_bounds__(256) void gemm_in_count_kernel(
    const float* __restrict__ A, const float* __restrict__ B,
    const float* __restrict__ bias, _Float16* __restrict__ C, int M,
    const int* __restrict__ idx_i, int* __restrict__ counts, int P,
    int gemm_blocks) {
    if ((int)blockIdx.x < gemm_blocks) {
        gemm_mfma_body<true, false, _Float16>(A, B, bias, C, M, blockIdx.x);
    } else {
        const int nthr = (gridDim.x - gemm_blocks) * 256;
        for (int p = (blockIdx.x - gemm_blocks) * 256 + threadIdx.x; p < P;
             p += nthr)
            atomicAdd(&counts[idx_i[p]], 1);
    }
}

__global__ __launch_bounds__(256) void gemm_out_kernel(
    const float* __restrict__ A, const float* __restrict__ B,
    const float* __restrict__ bias, float* __restrict__ C, int M) {
    gemm_mfma_body<false, true, float>(A, B, bias, C, M, blockIdx.x);
}

// ---- one-kernel segment allocation: block scan + global bump (order-free) ----
__global__ __launch_bounds__(256) void alloc_starts_kernel(
    const int* __restrict__ counts, int* __restrict__ starts,
    int* __restrict__ cursor, int* __restrict__ gtot, int N) {
    __shared__ int s[256];
    __shared__ int base;
    const int t = threadIdx.x, g = blockIdx.x * 256 + t;
    const int c = g < N ? counts[g] : 0;
    s[t] = c;
    __syncthreads();
    for (int o = 1; o < 256; o <<= 1) {
        int v = t >= o ? s[t - o] : 0;
        __syncthreads();
        s[t] += v;
        __syncthreads();
    }
    if (t == 255) base = atomicAdd(gtot, s[255]);
    __syncthreads();
    const int excl = base + s[t] - c;
    if (g < N) {
        starts[g] = excl;
        cursor[g] = excl;
    }
}

// ---- fill: scatter edge payload into segment-sorted order ----
// EF path: ef[pos] = 24 f16 {f_ij[0..19], 1.0(bias mult), 0,0,0}; meta = {jb, rc}.
// fallback: pidx[pos] = p (gather re-reads f_ij f32 via indirection).
template <bool EF>
__global__ __launch_bounds__(256) void fill_kernel(
    const int* __restrict__ idx_i, const int* __restrict__ idx_j,
    const float* __restrict__ rcut, const float* __restrict__ f_ij,
    int* __restrict__ cursor, _Float16* __restrict__ ef,
    int2* __restrict__ meta, int* __restrict__ pidx, int P) {
    int p = blockIdx.x * 256 + threadIdx.x;
    if (p >= P) return;
    const int i = idx_i[p];
    const int pos = atomicAdd(&cursor[i], 1);
    meta[pos] = make_int2(idx_j[p] << 7, __float_as_int(rcut[p]));
    if (EF) {
        const float* fr = f_ij + (size_t)p * 20;
        _Float16 hb[24];
#pragma unroll
        for (int r = 0; r < 20; r += 4) {
            float4 v = *(const float4*)(fr + r);
            hb[r] = (_Float16)v.x; hb[r + 1] = (_Float16)v.y;
            hb[r + 2] = (_Float16)v.z; hb[r + 3] = (_Float16)v.w;
        }
        hb[20] = (_Float16)1.0f; hb[21] = (_Float16)0.0f;
        hb[22] = (_Float16)0.0f; hb[23] = (_Float16)0.0f;
        _Float16* dst = ef + (size_t)pos * 24;
        *(half8*)dst = *(half8*)hb;
        *(half8*)(dst + 8) = *(half8*)(hb + 8);
        *(half8*)(dst + 16) = *(half8*)(hb + 16);
    } else {
        pidx[pos] = p;
    }
}

// ---- gather: ONE wave per atom (all 128 features), 16 edges per MFMA chunk.
//      h16 is in hperm layout: per chunk the hv loads are 4 instructions, each
//      reading 16 full 64B lines (4 q-lanes x 16B contiguous per edge row).
//      ef/meta reads are pos-consecutive (coalesced). meta prefetched 2 deep
//      (so hv addresses never wait on a just-issued meta load), hv 1 deep. ----
template <bool EF>
__global__ __launch_bounds__(256) void gather_mfma_kernel(
    const _Float16* __restrict__ ef, const int2* __restrict__ meta,
    const int* __restrict__ pidx, const float* __restrict__ f_ij,
    const float* __restrict__ Wf, const float* __restrict__ bf,
    const _Float16* __restrict__ h16, const int* __restrict__ starts,
    const int* __restrict__ counts, float* __restrict__ agg, int N) {
    const int lane = threadIdx.x & 63;
    const int gwave = (blockIdx.x * 256 + threadIdx.x) >> 6;
    const int nwaves = (gridDim.x * 256) >> 6;
    const int l15 = lane & 15, q = lane >> 4;

    // A-fragments: W_filter rows (feature m = t*16 + l15), bias at k=20.
    half8 wfr[8];
#pragma unroll
    for (int t = 0; t < 8; ++t) {
        const float* wr = Wf + (size_t)(t * 16 + l15) * 20;
        float v[8];
#pragma unroll
        for (int j = 0; j < 8; ++j) {
            int k = q * 8 + j;
            v[j] = (k < 20) ? wr[k] : ((k == 20) ? bf[t * 16 + l15] : 0.0f);
        }
        wfr[t] = (half8){(_Float16)v[0], (_Float16)v[1], (_Float16)v[2],
                         (_Float16)v[3], (_Float16)v[4], (_Float16)v[5],
                         (_Float16)v[6], (_Float16)v[7]};
    }
    const float4v zero = {0.f, 0.f, 0.f, 0.f};

    for (int i = gwave; i < N; i += nwaves) {
        const int s = __builtin_amdgcn_readfirstlane(starts[i]);
        const int cnt = __builtin_amdgcn_readfirstlane(counts[i]);
        const int e = s + cnt;
        float4v acc[8];
#pragma unroll
        for (int t = 0; t < 8; ++t) acc[t] = zero;

        if (cnt > 0) {
            // stage chunk0 meta/ef
            int pos0 = min(s + l15, e - 1);
            int2 mt_c = meta[pos0];
            half8 bf_c = {};
            int p_c = 0;
            if (EF) {
                if (q < 3) bf_c = *(const half8*)(ef + (size_t)pos0 * 24 + q * 8);
            } else {
                p_c = pidx[pos0];
            }
            // stage chunk1 meta/ef
            int2 mt_n = mt_c;
            half8 bf_n = bf_c;
            int p_n = p_c;
            if (s + 16 < e) {
                int pos1 = min(s + 16 + l15, e - 1);
                mt_n = meta[pos1];
                if (EF) {
                    if (q < 3) bf_n = *(const half8*)(ef + (size_t)pos1 * 24 + q * 8);
                } else {
                    p_n = pidx[pos1];
                }
            }
            // stage chunk0 h-row (lane reads 64B contiguous: 4 x half8)
            half8 hv_c[4];
            {
                const _Float16* hp = h16 + mt_c.x + q * 8;
#pragma unroll
                for (int c4 = 0; c4 < 4; ++c4)
                    hv_c[c4] = *(const half8*)(hp + c4 * 32);
            }

            for (int c0 = s; c0 < e; c0 += 16) {
                // issue next chunk's h-row gather (mt_n arrived a chunk ago)
                half8 hv_n[4];
                if (c0 + 16 < e) {
                    const _Float16* hp = h16 + mt_n.x + q * 8;
#pragma unroll
                    for (int c4 = 0; c4 < 4; ++c4)
                        hv_n[c4] = *(const half8*)(hp + c4 * 32);
                }
                // prefetch meta/ef two chunks ahead
                int2 mt_n2 = mt_n;
                half8 bf_n2 = bf_n;
                int p_n2 = p_n;
                if (c0 + 32 < e) {
                    int pos2 = min(c0 + 32 + l15, e - 1);
                    mt_n2 = meta[pos2];
                    if (EF) {
                        if (q < 3) bf_n2 = *(const half8*)(ef + (size_t)pos2 * 24 + q * 8);
                    } else {
                        p_n2 = pidx[pos2];
                    }
                }
                if (!EF) {  // build B-fragment from f32 f_ij (fallback)
                    const float* fp = f_ij + (size_t)p_c * 20;
                    float b0 = 0.f, b1 = 0.f, b2 = 0.f, b3 = 0.f;
                    float b4 = 0.f, b5 = 0.f, b6 = 0.f, b7 = 0.f;
                    if (q <= 2) {
                        float4 a = *(const float4*)(fp + q * 8);
                        b0 = a.x; b1 = a.y; b2 = a.z; b3 = a.w;
                    }
                    if (q <= 1) {
                        float4 bb = *(const float4*)(fp + q * 8 + 4);
                        b4 = bb.x; b5 = bb.y; b6 = bb.z; b7 = bb.w;
                    }
                    if (q == 2) b4 = 1.0f;
                    bf_c = (half8){(_Float16)b0, (_Float16)b1, (_Float16)b2,
                                   (_Float16)b3, (_Float16)b4, (_Float16)b5,
                                   (_Float16)b6, (_Float16)b7};
                }
                const float rc = (c0 + l15 < e) ? __int_as_float(mt_c.y) : 0.0f;
#pragma unroll
                for (int t = 0; t < 8; ++t) {
                    float4v d = __builtin_amdgcn_mfma_f32_16x16x32_f16(
                        wfr[t], bf_c, zero, 0, 0, 0);
                    const int hc = t >> 1, hb = (t & 1) * 4;
#pragma unroll
                    for (int r = 0; r < 4; ++r) {
                        float w = sspf(d[r]) * rc;
                        acc[t][r] = fmaf(w, (float)hv_c[hc][hb + r], acc[t][r]);
                    }
                }
                // rotate pipeline registers
                mt_c = mt_n; mt_n = mt_n2;
                bf_c = bf_n; bf_n = bf_n2;
                p_c = p_n;   p_n = p_n2;
#pragma unroll
                for (int c4 = 0; c4 < 4; ++c4) hv_c[c4] = hv_n[c4];
            }
        }
        // reduce across the 16-edge (l15) dimension
#pragma unroll
        for (int m = 1; m <= 8; m <<= 1)
#pragma unroll
            for (int t = 0; t < 8; ++t)
#pragma unroll
                for (int r = 0; r < 4; ++r)
                    acc[t][r] += __shfl_xor(acc[t][r], m, 64);
        if (l15 == 0) {
#pragma unroll
            for (int t = 0; t < 8; ++t) {
                float4 o = {acc[t][0], acc[t][1], acc[t][2], acc[t][3]};
                *(float4*)(agg + (size_t)i * 128 + t * 16 + q * 4) = o;
            }
        }
    }
}

extern "C" void kernel_launch(void* const* d_in, const int* in_sizes, int n_in,
                              void* d_out, int out_size, void* d_ws, size_t ws_size,
                              hipStream_t stream) {
    const float* x     = (const float*)d_in[0];
    const float* f_ij  = (const float*)d_in[1];
    const int*   idx_i = (const int*)d_in[2];
    const int*   idx_j = (const int*)d_in[3];
    const float* rcut  = (const float*)d_in[4];
    const float* W_in  = (const float*)d_in[5];
    const float* b_in  = (const float*)d_in[6];
    const float* W_f   = (const float*)d_in[7];
    const float* b_f   = (const float*)d_in[8];
    const float* W_out = (const float*)d_in[9];
    const float* b_out = (const float*)d_in[10];

    const int N = in_sizes[0] / 128;  // 50000
    const int P = in_sizes[2];        // 1600000

    // workspace layout (16B-aligned chunks)
    char* ws = (char*)d_ws;
    size_t off = 0;
    auto alloc = [&](size_t bytes) {
        void* ptr = ws + off;
        off += (bytes + 15) & ~(size_t)15;
        return ptr;
    };
    int* counts  = (int*)alloc((size_t)N * 4 + 16);  // gtot rides at counts[N..]
    int* gtot    = counts + N;
    int* starts  = (int*)alloc((size_t)N * 4);
    int* cursor  = (int*)alloc((size_t)N * 4);
    _Float16* h16 = (_Float16*)alloc((size_t)N * 128 * 2);
    int2* meta   = (int2*)alloc((size_t)P * 8);
    size_t base_need = off;
    const bool use_ef = (base_need + (size_t)P * 24 * 2 + 64) <= ws_size;
    _Float16* ef = nullptr;
    int* pidx = nullptr;
    if (use_ef) ef = (_Float16*)alloc((size_t)P * 24 * 2 + 64);
    else        pidx = (int*)alloc((size_t)P * 4);

    float* agg = (float*)d_out;  // gather writes agg; gemm_out runs in-place

    const int mblocks = (N + 63) / 64;  // 782
    const int cblocks = 768;
    const int NB = (N + 255) / 256;

    hipMemsetAsync(counts, 0, (size_t)N * 4 + 16, stream);  // counts + gtot
    gemm_in_count_kernel<<<mblocks + cblocks, 256, 0, stream>>>(
        x, W_in, b_in, h16, N, idx_i, counts, P, mblocks);
    alloc_starts_kernel<<<NB, 256, 0, stream>>>(counts, starts, cursor, gtot, N);
    if (use_ef) {
        fill_kernel<true><<<(P + 255) / 256, 256, 0, stream>>>(
            idx_i, idx_j, rcut, f_ij, cursor, ef, meta, pidx, P);
        gather_mfma_kernel<true><<<4096, 256, 0, stream>>>(
            ef, meta, pidx, f_ij, W_f, b_f, h16, starts, counts, agg, N);
    } else {
        fill_kernel<false><<<(P + 255) / 256, 256, 0, stream>>>(
            idx_i, idx_j, rcut, f_ij, cursor, ef, meta, pidx, P);
        gather_mfma_kernel<false><<<4096, 256, 0, stream>>>(
            ef, meta, pidx, f_ij, W_f, b_f, h16, starts, counts, agg, N);
    }
    gemm_out_kernel<<<mblocks, 256, 0, stream>>>(agg, W_out, b_out, (float*)d_out, N);
}

// Round 5
// 677.084 us; speedup vs baseline: 1.5115x; 1.0267x over previous
//
#include <hip/hip_runtime.h>
#include <hip/hip_bf16.h>

static constexpr float kLog2 = 0.6931471805599453f;

__device__ __forceinline__ float sspf(float x) {
    return fmaxf(x, 0.0f) + __logf(1.0f + __expf(-fabsf(x))) - kLog2;
}

typedef __attribute__((ext_vector_type(8))) _Float16 half8;
typedef __attribute__((ext_vector_type(4))) _Float16 half4v;
typedef __attribute__((ext_vector_type(4))) float float4v;

// Feature permutation for h16 rows (producer: gemm_in, consumer: gather).
// For n = t*16 + q*4 + r (t<8,q<4,r<4): hperm(n) = (t>>1)*32 + q*8 + (t&1)*4 + r.
// Gather lane q of wave-half fh reads its 16 features for tiles t'=0..3 as two
// contiguous half8 loads at h16 + jb + fh*64 + q*8 (+0, +32): the 4 q-lanes of
// one edge row cover one aligned 64B line per load instruction.
__device__ __forceinline__ int hperm(int n) {
    return ((n >> 6) << 6) | (((n >> 5) & 1) << 5) | (((n >> 2) & 3) << 3) |
           (((n >> 4) & 1) << 2) | (n & 3);
}

// ---------------- dense GEMMs (f16 MFMA 16x16x32, whole K in LDS) ----------
template <bool PERM, bool ACT, typename OUT>
__device__ __forceinline__ void gemm_mfma_body(const float* __restrict__ A,
                                               const float* __restrict__ B,
                                               const float* __restrict__ bias,
                                               OUT* __restrict__ C, int M,
                                               int blockid) {
    constexpr int LDH = 136;
    __shared__ _Float16 Als[64 * LDH];
    __shared__ _Float16 Bls[128 * LDH];
    const int tid = threadIdx.x;
    const int rowbase = blockid * 64;
#pragma unroll
    for (int j = 0; j < 8; ++j) {
        int idx = j * 256 + tid;
        int r = idx >> 5, c4 = (idx & 31) << 2;
        int rg = rowbase + r;
        rg = rg < M ? rg : (M - 1);
        float4 v = *(const float4*)(A + (size_t)rg * 128 + c4);
        half4v hv = {(_Float16)v.x, (_Float16)v.y, (_Float16)v.z, (_Float16)v.w};
        *(half4v*)&Als[r * LDH + c4] = hv;
    }
#pragma unroll
    for (int j = 0; j < 16; ++j) {
        int idx = j * 256 + tid;
        int r = idx >> 5, c4 = (idx & 31) << 2;
        float4 v = *(const float4*)(B + (size_t)r * 128 + c4);
        half4v hv = {(_Float16)v.x, (_Float16)v.y, (_Float16)v.z, (_Float16)v.w};
        *(half4v*)&Bls[r * LDH + c4] = hv;
    }
    __syncthreads();

    const int wave = tid >> 6, lane = tid & 63;
    const int l15 = lane & 15, q = lane >> 4;
    float4v acc[8];
#pragma unroll
    for (int nt = 0; nt < 8; ++nt) acc[nt] = (float4v){0.f, 0.f, 0.f, 0.f};
    const int am = wave * 16 + l15;
#pragma unroll
    for (int kk = 0; kk < 4; ++kk) {
        half8 af = *(const half8*)&Als[am * LDH + kk * 32 + q * 8];
#pragma unroll
        for (int nt = 0; nt < 8; ++nt) {
            half8 bfv = *(const half8*)&Bls[(nt * 16 + l15) * LDH + kk * 32 + q * 8];
            acc[nt] = __builtin_amdgcn_mfma_f32_16x16x32_f16(af, bfv, acc[nt], 0, 0, 0);
        }
    }
#pragma unroll
    for (int nt = 0; nt < 8; ++nt) {
        int n = nt * 16 + l15;
        float bv = bias[n];
        const int pn = PERM ? hperm(n) : n;
#pragma unroll
        for (int r = 0; r < 4; ++r) {
            int m = rowbase + wave * 16 + q * 4 + r;
            if (m < M) {
                float v = acc[nt][r] + bv;
                if (ACT) v = sspf(v);
                C[(size_t)m * 128 + pn] = (OUT)v;
            }
        }
    }
}

__global__ __launch_bounds__(256) void gemm_in_count_kernel(
    const float* __restrict__ A, const float* __restrict__ B,
    const float* __restrict__ bias, _Float16* __restrict__ C, int M,
    const int* __restrict__ idx_i, int* __restrict__ counts, int P,
    int gemm_blocks) {
    if ((int)blockIdx.x < gemm_blocks) {
        gemm_mfma_body<true, false, _Float16>(A, B, bias, C, M, blockIdx.x);
    } else {
        const int nthr = (gridDim.x - gemm_blocks) * 256;
        for (int p = (blockIdx.x - gemm_blocks) * 256 + threadIdx.x; p < P;
             p += nthr)
            atomicAdd(&counts[idx_i[p]], 1);
    }
}

__global__ __launch_bounds__(256) void gemm_out_kernel(
    const float* __restrict__ A, const float* __restrict__ B,
    const float* __restrict__ bias, float* __restrict__ C, int M) {
    gemm_mfma_body<false, true, float>(A, B, bias, C, M, blockIdx.x);
}

// ---- one-kernel segment allocation: block scan + global bump (order-free) ----
__global__ __launch_bounds__(256) void alloc_starts_kernel(
    const int* __restrict__ counts, int* __restrict__ starts,
    int* __restrict__ cursor, int* __restrict__ gtot, int N) {
    __shared__ int s[256];
    __shared__ int base;
    const int t = threadIdx.x, g = blockIdx.x * 256 + t;
    const int c = g < N ? counts[g] : 0;
    s[t] = c;
    __syncthreads();
    for (int o = 1; o < 256; o <<= 1) {
        int v = t >= o ? s[t - o] : 0;
        __syncthreads();
        s[t] += v;
        __syncthreads();
    }
    if (t == 255) base = atomicAdd(gtot, s[255]);
    __syncthreads();
    const int excl = base + s[t] - c;
    if (g < N) {
        starts[g] = excl;
        cursor[g] = excl;
    }
}

// ---- fill16: scatter ONLY a 16B record per edge into segment order.
//      {jb = idx_j*128, rc bits, p, 0}. No f_ij touch, no ef materialization:
//      cuts fill's fabric requests from ~4-5M lines to ~1M. ----
__global__ __launch_bounds__(256) void fill16_kernel(
    const int* __restrict__ idx_i, const int* __restrict__ idx_j,
    const float* __restrict__ rcut, int* __restrict__ cursor,
    int4* __restrict__ meta, int P) {
    int p = blockIdx.x * 256 + threadIdx.x;
    if (p >= P) return;
    const int pos = atomicAdd(&cursor[idx_i[p]], 1);
    meta[pos] = make_int4(idx_j[p] << 7, __float_as_int(rcut[p]), p, 0);
}

// ---- gather: 2 waves per atom (64 features each), 16 edges per MFMA chunk.
//      Reads f_ij f32 DIRECTLY (random 80B rows = exactly 2 aligned lines/edge,
//      prefetched 2 chunks deep via meta16's p). Twin waves issue identical
//      f_ij/meta reads ~simultaneously -> second read is an L2 hit (proven by
//      R1's FETCH == R0's FETCH). h16 read via hperm full-line half8 loads. ----
__global__ __launch_bounds__(256) void gather_direct_kernel(
    const int4* __restrict__ meta, const float* __restrict__ f_ij,
    const float* __restrict__ Wf, const float* __restrict__ bf,
    const _Float16* __restrict__ h16, const int* __restrict__ starts,
    const int* __restrict__ counts, float* __restrict__ agg, int N) {
    const int lane = threadIdx.x & 63;
    const int gwave = (blockIdx.x * 256 + threadIdx.x) >> 6;
    const int nwaves = (gridDim.x * 256) >> 6;
    const int l15 = lane & 15, q = lane >> 4;
    const int fh = gwave & 1;       // feature half: tiles [fh*4, fh*4+4)
    const int fbase = fh * 64;

    // A-fragments: W_filter rows for this wave's 4 tiles, bias at k=20.
    half8 wfr[4];
#pragma unroll
    for (int t = 0; t < 4; ++t) {
        const int n = fbase + t * 16 + l15;
        const float* wr = Wf + (size_t)n * 20;
        float v[8];
#pragma unroll
        for (int j = 0; j < 8; ++j) {
            int k = q * 8 + j;
            v[j] = (k < 20) ? wr[k] : ((k == 20) ? bf[n] : 0.0f);
        }
        wfr[t] = (half8){(_Float16)v[0], (_Float16)v[1], (_Float16)v[2],
                         (_Float16)v[3], (_Float16)v[4], (_Float16)v[5],
                         (_Float16)v[6], (_Float16)v[7]};
    }
    const float4v zero = {0.f, 0.f, 0.f, 0.f};
    const _Float16* hws = h16 + fbase + q * 8;  // + jb per edge (hperm layout)

    for (int u = gwave; u < 2 * N; u += nwaves) {
        const int i = u >> 1;
        const int s = __builtin_amdgcn_readfirstlane(starts[i]);
        const int cnt = __builtin_amdgcn_readfirstlane(counts[i]);
        const int e = s + cnt;
        float4v acc[4];
#pragma unroll
        for (int t = 0; t < 4; ++t) acc[t] = zero;

        if (cnt > 0) {
            // prologue: meta for chunk0 and chunk1 (issued together)
            int4 mt_c = meta[min(s + l15, e - 1)];
            int4 mt_n = (s + 16 < e) ? meta[min(s + 16 + l15, e - 1)] : mt_c;
            // f_ij rows for chunk0 (fa/fb_c) and chunk1 (fa/fb_p, in flight)
            float4 fa_c = {0, 0, 0, 0}, fb_c = {0, 0, 0, 0};
            float4 fa_p = {0, 0, 0, 0}, fb_p = {0, 0, 0, 0};
            {
                const float* fp = f_ij + (size_t)mt_c.z * 20;
                if (q <= 2) fa_c = *(const float4*)(fp + q * 8);
                if (q <= 1) fb_c = *(const float4*)(fp + q * 8 + 4);
                const float* fp2 = f_ij + (size_t)mt_n.z * 20;
                if (q <= 2) fa_p = *(const float4*)(fp2 + q * 8);
                if (q <= 1) fb_p = *(const float4*)(fp2 + q * 8 + 4);
            }

            for (int c0 = s; c0 < e; c0 += 16) {
                // h-row loads for this chunk (lane reads 2x16B of a 64B line)
                const _Float16* hp = hws + mt_c.x;
                half8 hv0 = *(const half8*)hp;
                half8 hv1 = *(const half8*)(hp + 32);
                // meta 2 chunks ahead
                int4 mt_n2 = mt_n;
                if (c0 + 32 < e) mt_n2 = meta[min(c0 + 32 + l15, e - 1)];
                // build B-fragment from this chunk's f32 f_ij row
                float b0 = 0.f, b1 = 0.f, b2 = 0.f, b3 = 0.f;
                float b4 = 0.f, b5 = 0.f, b6 = 0.f, b7 = 0.f;
                if (q <= 2) { b0 = fa_c.x; b1 = fa_c.y; b2 = fa_c.z; b3 = fa_c.w; }
                if (q <= 1) { b4 = fb_c.x; b5 = fb_c.y; b6 = fb_c.z; b7 = fb_c.w; }
                if (q == 2) b4 = 1.0f;
                const half8 bfc = (half8){(_Float16)b0, (_Float16)b1, (_Float16)b2,
                                          (_Float16)b3, (_Float16)b4, (_Float16)b5,
                                          (_Float16)b6, (_Float16)b7};
                const float rc = (c0 + l15 < e) ? __int_as_float(mt_c.y) : 0.0f;
#pragma unroll
                for (int t = 0; t < 4; ++t) {
                    float4v d = __builtin_amdgcn_mfma_f32_16x16x32_f16(
                        wfr[t], bfc, zero, 0, 0, 0);
                    const half8& hv = (t < 2) ? hv0 : hv1;
                    const int hb = (t & 1) * 4;
#pragma unroll
                    for (int r = 0; r < 4; ++r) {
                        float w = sspf(d[r]) * rc;
                        acc[t][r] = fmaf(w, (float)hv[hb + r], acc[t][r]);
                    }
                }
                // rotate pipeline, then issue f_ij for chunk c0+32 (mt_n2.z
                // was issued at top of this iteration -> arrived by now).
                mt_c = mt_n; mt_n = mt_n2;
                fa_c = fa_p; fb_c = fb_p;
                if (c0 + 32 < e) {
                    const float* fp = f_ij + (size_t)mt_n.z * 20;
                    if (q <= 2) fa_p = *(const float4*)(fp + q * 8);
                    if (q <= 1) fb_p = *(const float4*)(fp + q * 8 + 4);
                }
            }
        }
        // reduce across the 16-edge (l15) dimension
#pragma unroll
        for (int m = 1; m <= 8; m <<= 1)
#pragma unroll
            for (int t = 0; t < 4; ++t)
#pragma unroll
                for (int r = 0; r < 4; ++r)
                    acc[t][r] += __shfl_xor(acc[t][r], m, 64);
        if (l15 == 0) {
#pragma unroll
            for (int t = 0; t < 4; ++t) {
                float4 o = {acc[t][0], acc[t][1], acc[t][2], acc[t][3]};
                *(float4*)(agg + (size_t)i * 128 + fbase + t * 16 + q * 4) = o;
            }
        }
    }
}

extern "C" void kernel_launch(void* const* d_in, const int* in_sizes, int n_in,
                              void* d_out, int out_size, void* d_ws, size_t ws_size,
                              hipStream_t stream) {
    const float* x     = (const float*)d_in[0];
    const float* f_ij  = (const float*)d_in[1];
    const int*   idx_i = (const int*)d_in[2];
    const int*   idx_j = (const int*)d_in[3];
    const float* rcut  = (const float*)d_in[4];
    const float* W_in  = (const float*)d_in[5];
    const float* b_in  = (const float*)d_in[6];
    const float* W_f   = (const float*)d_in[7];
    const float* b_f   = (const float*)d_in[8];
    const float* W_out = (const float*)d_in[9];
    const float* b_out = (const float*)d_in[10];

    const int N = in_sizes[0] / 128;  // 50000
    const int P = in_sizes[2];        // 1600000

    // workspace layout (16B-aligned chunks); total ~39 MB (<< prior ~115 MB)
    char* ws = (char*)d_ws;
    size_t off = 0;
    auto alloc = [&](size_t bytes) {
        void* ptr = ws + off;
        off += (bytes + 15) & ~(size_t)15;
        return ptr;
    };
    int* counts  = (int*)alloc((size_t)N * 4 + 16);  // gtot rides at counts[N..]
    int* gtot    = counts + N;
    int* starts  = (int*)alloc((size_t)N * 4);
    int* cursor  = (int*)alloc((size_t)N * 4);
    _Float16* h16 = (_Float16*)alloc((size_t)N * 128 * 2);
    int4* meta   = (int4*)alloc((size_t)P * 16);

    float* agg = (float*)d_out;  // gather writes agg f32; gemm_out runs in-place

    const int mblocks = (N + 63) / 64;  // 782
    const int cblocks = 768;
    const int NB = (N + 255) / 256;

    hipMemsetAsync(counts, 0, (size_t)N * 4 + 16, stream);  // counts + gtot
    gemm_in_count_kernel<<<mblocks + cblocks, 256, 0, stream>>>(
        x, W_in, b_in, h16, N, idx_i, counts, P, mblocks);
    alloc_starts_kernel<<<NB, 256, 0, stream>>>(counts, starts, cursor, gtot, N);
    fill16_kernel<<<(P + 255) / 256, 256, 0, stream>>>(
        idx_i, idx_j, rcut, cursor, meta, P);
    gather_direct_kernel<<<4096, 256, 0, stream>>>(
        meta, f_ij, W_f, b_f, h16, starts, counts, agg, N);
    gemm_out_kernel<<<mblocks, 256, 0, stream>>>(agg, W_out, b_out, (float*)d_out, N);
}

// Round 6
// 614.840 us; speedup vs baseline: 1.6645x; 1.1012x over previous
//
#include <hip/hip_runtime.h>
#include <hip/hip_bf16.h>

static constexpr float kLog2 = 0.6931471805599453f;

__device__ __forceinline__ float sspf(float x) {
    return fmaxf(x, 0.0f) + __logf(1.0f + __expf(-fabsf(x))) - kLog2;
}

typedef __attribute__((ext_vector_type(8))) _Float16 half8;
typedef __attribute__((ext_vector_type(4))) _Float16 half4v;
typedef __attribute__((ext_vector_type(4))) float float4v;

// Feature permutation for h16 rows (producer: gemm_in, consumer: gather).
// For n = fh*64 + t*16 + q*4 + r: hperm(n) = fh*64 + (t>>1)*32 + q*8 + (t&1)*4 + r.
// Gather lane q of wave-half fh reads its 16 features for tiles t=0..3 as two
// contiguous half8 loads at h16 + jb + fh*64 + q*8 (+0, +32): the 4 q-lanes of
// one edge row cover one aligned 64B line per load instruction.
__device__ __forceinline__ int hperm(int n) {
    return ((n >> 6) << 6) | (((n >> 5) & 1) << 5) | (((n >> 2) & 3) << 3) |
           (((n >> 4) & 1) << 2) | (n & 3);
}

// ---------------- dense GEMMs (f16 MFMA 16x16x32, whole K in LDS) ----------
template <bool PERM, bool ACT, typename OUT>
__device__ __forceinline__ void gemm_mfma_body(const float* __restrict__ A,
                                               const float* __restrict__ B,
                                               const float* __restrict__ bias,
                                               OUT* __restrict__ C, int M,
                                               int blockid) {
    constexpr int LDH = 136;
    __shared__ _Float16 Als[64 * LDH];
    __shared__ _Float16 Bls[128 * LDH];
    const int tid = threadIdx.x;
    const int rowbase = blockid * 64;
#pragma unroll
    for (int j = 0; j < 8; ++j) {
        int idx = j * 256 + tid;
        int r = idx >> 5, c4 = (idx & 31) << 2;
        int rg = rowbase + r;
        rg = rg < M ? rg : (M - 1);
        float4 v = *(const float4*)(A + (size_t)rg * 128 + c4);
        half4v hv = {(_Float16)v.x, (_Float16)v.y, (_Float16)v.z, (_Float16)v.w};
        *(half4v*)&Als[r * LDH + c4] = hv;
    }
#pragma unroll
    for (int j = 0; j < 16; ++j) {
        int idx = j * 256 + tid;
        int r = idx >> 5, c4 = (idx & 31) << 2;
        float4 v = *(const float4*)(B + (size_t)r * 128 + c4);
        half4v hv = {(_Float16)v.x, (_Float16)v.y, (_Float16)v.z, (_Float16)v.w};
        *(half4v*)&Bls[r * LDH + c4] = hv;
    }
    __syncthreads();

    const int wave = tid >> 6, lane = tid & 63;
    const int l15 = lane & 15, q = lane >> 4;
    float4v acc[8];
#pragma unroll
    for (int nt = 0; nt < 8; ++nt) acc[nt] = (float4v){0.f, 0.f, 0.f, 0.f};
    const int am = wave * 16 + l15;
#pragma unroll
    for (int kk = 0; kk < 4; ++kk) {
        half8 af = *(const half8*)&Als[am * LDH + kk * 32 + q * 8];
#pragma unroll
        for (int nt = 0; nt < 8; ++nt) {
            half8 bfv = *(const half8*)&Bls[(nt * 16 + l15) * LDH + kk * 32 + q * 8];
            acc[nt] = __builtin_amdgcn_mfma_f32_16x16x32_f16(af, bfv, acc[nt], 0, 0, 0);
        }
    }
#pragma unroll
    for (int nt = 0; nt < 8; ++nt) {
        int n = nt * 16 + l15;
        float bv = bias[n];
        const int pn = PERM ? hperm(n) : n;
#pragma unroll
        for (int r = 0; r < 4; ++r) {
            int m = rowbase + wave * 16 + q * 4 + r;
            if (m < M) {
                float v = acc[nt][r] + bv;
                if (ACT) v = sspf(v);
                C[(size_t)m * 128 + pn] = (OUT)v;
            }
        }
    }
}

__global__ __launch_bounds__(256) void gemm_in_count_kernel(
    const float* __restrict__ A, const float* __restrict__ B,
    const float* __restrict__ bias, _Float16* __restrict__ C, int M,
    const int* __restrict__ idx_i, int* __restrict__ counts, int P,
    int gemm_blocks) {
    if ((int)blockIdx.x < gemm_blocks) {
        gemm_mfma_body<true, false, _Float16>(A, B, bias, C, M, blockIdx.x);
    } else {
        const int nthr = (gridDim.x - gemm_blocks) * 256;
        for (int p = (blockIdx.x - gemm_blocks) * 256 + threadIdx.x; p < P;
             p += nthr)
            atomicAdd(&counts[idx_i[p]], 1);
    }
}

__global__ __launch_bounds__(256) void gemm_out_kernel(
    const float* __restrict__ A, const float* __restrict__ B,
    const float* __restrict__ bias, float* __restrict__ C, int M) {
    gemm_mfma_body<false, true, float>(A, B, bias, C, M, blockIdx.x);
}

// ---- one-kernel segment allocation: block scan + global bump (order-free) ----
__global__ __launch_bounds__(256) void alloc_starts_kernel(
    const int* __restrict__ counts, int* __restrict__ starts,
    int* __restrict__ cursor, int* __restrict__ gtot, int N) {
    __shared__ int s[256];
    __shared__ int base;
    const int t = threadIdx.x, g = blockIdx.x * 256 + t;
    const int c = g < N ? counts[g] : 0;
    s[t] = c;
    __syncthreads();
    for (int o = 1; o < 256; o <<= 1) {
        int v = t >= o ? s[t - o] : 0;
        __syncthreads();
        s[t] += v;
        __syncthreads();
    }
    if (t == 255) base = atomicAdd(gtot, s[255]);
    __syncthreads();
    const int excl = base + s[t] - c;
    if (g < N) {
        starts[g] = excl;
        cursor[g] = excl;
    }
}

// ---- fill48: one 48B record per edge in segment-sorted order.
//      bytes [0..39] = f16 f_ij[0..19]; [40..43] = f32 rcut; [44..47] = jb.
//      Single stream replaces R1's separate ef(48B-padded) + meta(8B). ----
__global__ __launch_bounds__(256) void fill48_kernel(
    const int* __restrict__ idx_i, const int* __restrict__ idx_j,
    const float* __restrict__ rcut, const float* __restrict__ f_ij,
    int* __restrict__ cursor, char* __restrict__ rec, int P) {
    int p = blockIdx.x * 256 + threadIdx.x;
    if (p >= P) return;
    const int pos = atomicAdd(&cursor[idx_i[p]], 1);
    const float* fr = f_ij + (size_t)p * 20;
    float4 v0 = *(const float4*)(fr + 0);
    float4 v1 = *(const float4*)(fr + 4);
    float4 v2 = *(const float4*)(fr + 8);
    float4 v3 = *(const float4*)(fr + 12);
    float4 v4 = *(const float4*)(fr + 16);
    half8 h0 = {(_Float16)v0.x, (_Float16)v0.y, (_Float16)v0.z, (_Float16)v0.w,
                (_Float16)v1.x, (_Float16)v1.y, (_Float16)v1.z, (_Float16)v1.w};
    half8 h1 = {(_Float16)v2.x, (_Float16)v2.y, (_Float16)v2.z, (_Float16)v2.w,
                (_Float16)v3.x, (_Float16)v3.y, (_Float16)v3.z, (_Float16)v3.w};
    _Float16 t4[4] = {(_Float16)v4.x, (_Float16)v4.y, (_Float16)v4.z,
                      (_Float16)v4.w};
    int4 r2;
    r2.x = *(const int*)&t4[0];
    r2.y = *(const int*)&t4[2];
    r2.z = __float_as_int(rcut[p]);
    r2.w = idx_j[p] << 7;
    char* dst = rec + (size_t)pos * 48;
    *(half8*)dst = h0;
    *(half8*)(dst + 16) = h1;
    *(int4*)(dst + 32) = r2;
}

// ---- gather: 2 waves per atom (64 features each), 16 edges per MFMA chunk.
//      Per chunk: one exec-masked dwordx4 record load (q<3; 16B quarter each),
//      rc/jb broadcast from the q2 lane via shfl, two half8 h-loads in hperm
//      full-line layout. Records prefetched 2 deep, h-rows 1 deep. ----
__global__ __launch_bounds__(256) void gather_rec_kernel(
    const char* __restrict__ rec, const float* __restrict__ Wf,
    const float* __restrict__ bf, const _Float16* __restrict__ h16,
    const int* __restrict__ starts, const int* __restrict__ counts,
    float* __restrict__ agg, int N) {
    const int lane = threadIdx.x & 63;
    const int gwave = (blockIdx.x * 256 + threadIdx.x) >> 6;
    const int nwaves = (gridDim.x * 256) >> 6;
    const int l15 = lane & 15, q = lane >> 4;
    const int fh = gwave & 1;       // feature half: tiles [fh*4, fh*4+4)
    const int fbase = fh * 64;

    // A-fragments: W_filter rows for this wave's 4 tiles, bias at k=20.
    half8 wfr[4];
#pragma unroll
    for (int t = 0; t < 4; ++t) {
        const int n = fbase + t * 16 + l15;
        const float* wr = Wf + (size_t)n * 20;
        float v[8];
#pragma unroll
        for (int j = 0; j < 8; ++j) {
            int k = q * 8 + j;
            v[j] = (k < 20) ? wr[k] : ((k == 20) ? bf[n] : 0.0f);
        }
        wfr[t] = (half8){(_Float16)v[0], (_Float16)v[1], (_Float16)v[2],
                         (_Float16)v[3], (_Float16)v[4], (_Float16)v[5],
                         (_Float16)v[6], (_Float16)v[7]};
    }
    const float4v zero = {0.f, 0.f, 0.f, 0.f};
    const _Float16* hws = h16 + fbase + q * 8;  // + jb per edge (hperm layout)

    for (int u = gwave; u < 2 * N; u += nwaves) {
        const int i = u >> 1;
        const int s = __builtin_amdgcn_readfirstlane(starts[i]);
        const int cnt = __builtin_amdgcn_readfirstlane(counts[i]);
        const int e = s + cnt;
        float4v acc[4];
#pragma unroll
        for (int t = 0; t < 4; ++t) acc[t] = zero;

        if (cnt > 0) {
            // prologue: records for chunk0 and chunk1
            int4 r_c = {0, 0, 0, 0}, r_n = {0, 0, 0, 0};
            {
                int pos0 = min(s + l15, e - 1);
                if (q < 3) r_c = *(const int4*)(rec + (size_t)pos0 * 48 + q * 16);
            }
            if (s + 16 < e) {
                int pos1 = min(s + 16 + l15, e - 1);
                if (q < 3) r_n = *(const int4*)(rec + (size_t)pos1 * 48 + q * 16);
            } else {
                r_n = r_c;
            }
            // chunk0 rc/jb broadcast + h-row stage
            float rcv_c = __int_as_float(__shfl(r_c.z, 32 + l15, 64));
            int jb_c = __shfl(r_c.w, 32 + l15, 64);
            const _Float16* hp = hws + jb_c;
            half8 hv0_c = *(const half8*)hp;
            half8 hv1_c = *(const half8*)(hp + 32);

            for (int c0 = s; c0 < e; c0 += 16) {
                // next chunk's rc/jb + h-row (r_n arrived a chunk ago)
                float rcv_n = __int_as_float(__shfl(r_n.z, 32 + l15, 64));
                int jb_n = __shfl(r_n.w, 32 + l15, 64);
                half8 hv0_n = hv0_c, hv1_n = hv1_c;
                if (c0 + 16 < e) {
                    const _Float16* hp2 = hws + jb_n;
                    hv0_n = *(const half8*)hp2;
                    hv1_n = *(const half8*)(hp2 + 32);
                }
                // record two chunks ahead
                int4 r_n2 = r_n;
                if (c0 + 32 < e) {
                    int pos2 = min(c0 + 32 + l15, e - 1);
                    if (q < 3)
                        r_n2 = *(const int4*)(rec + (size_t)pos2 * 48 + q * 16);
                }
                // B-fragment from this chunk's record quarter
                half8 bfc = *(half8*)&r_c;   // q3: stays all-zero (never loaded)
                if (q == 2) {
                    bfc[4] = (_Float16)1.0f;  // bias multiplier at k=20
                    bfc[5] = (_Float16)0.0f;
                    bfc[6] = (_Float16)0.0f;
                    bfc[7] = (_Float16)0.0f;
                }
                const float rcm = (c0 + l15 < e) ? rcv_c : 0.0f;
#pragma unroll
                for (int t = 0; t < 4; ++t) {
                    float4v d = __builtin_amdgcn_mfma_f32_16x16x32_f16(
                        wfr[t], bfc, zero, 0, 0, 0);
                    const half8& hv = (t < 2) ? hv0_c : hv1_c;
                    const int hb = (t & 1) * 4;
#pragma unroll
                    for (int r = 0; r < 4; ++r) {
                        float w = sspf(d[r]) * rcm;
                        acc[t][r] = fmaf(w, (float)hv[hb + r], acc[t][r]);
                    }
                }
                // rotate pipeline registers
                r_c = r_n; r_n = r_n2;
                rcv_c = rcv_n;
                hv0_c = hv0_n; hv1_c = hv1_n;
            }
        }
        // reduce across the 16-edge (l15) dimension
#pragma unroll
        for (int m = 1; m <= 8; m <<= 1)
#pragma unroll
            for (int t = 0; t < 4; ++t)
#pragma unroll
                for (int r = 0; r < 4; ++r)
                    acc[t][r] += __shfl_xor(acc[t][r], m, 64);
        if (l15 == 0) {
#pragma unroll
            for (int t = 0; t < 4; ++t) {
                float4 o = {acc[t][0], acc[t][1], acc[t][2], acc[t][3]};
                *(float4*)(agg + (size_t)i * 128 + fbase + t * 16 + q * 4) = o;
            }
        }
    }
}

extern "C" void kernel_launch(void* const* d_in, const int* in_sizes, int n_in,
                              void* d_out, int out_size, void* d_ws, size_t ws_size,
                              hipStream_t stream) {
    const float* x     = (const float*)d_in[0];
    const float* f_ij  = (const float*)d_in[1];
    const int*   idx_i = (const int*)d_in[2];
    const int*   idx_j = (const int*)d_in[3];
    const float* rcut  = (const float*)d_in[4];
    const float* W_in  = (const float*)d_in[5];
    const float* b_in  = (const float*)d_in[6];
    const float* W_f   = (const float*)d_in[7];
    const float* b_f   = (const float*)d_in[8];
    const float* W_out = (const float*)d_in[9];
    const float* b_out = (const float*)d_in[10];

    const int N = in_sizes[0] / 128;  // 50000
    const int P = in_sizes[2];        // 1600000

    // workspace layout (16B-aligned chunks); ~90 MB total (R1 proved >=103 MB)
    char* ws = (char*)d_ws;
    size_t off = 0;
    auto alloc = [&](size_t bytes) {
        void* ptr = ws + off;
        off += (bytes + 15) & ~(size_t)15;
        return ptr;
    };
    int* counts  = (int*)alloc((size_t)N * 4 + 16);  // gtot rides at counts[N..]
    int* gtot    = counts + N;
    int* starts  = (int*)alloc((size_t)N * 4);
    int* cursor  = (int*)alloc((size_t)N * 4);
    _Float16* h16 = (_Float16*)alloc((size_t)N * 128 * 2);
    char* rec    = (char*)alloc((size_t)P * 48 + 64);

    float* agg = (float*)d_out;  // gather writes agg f32; gemm_out runs in-place

    const int mblocks = (N + 63) / 64;  // 782
    const int cblocks = 768;
    const int NB = (N + 255) / 256;

    hipMemsetAsync(counts, 0, (size_t)N * 4 + 16, stream);  // counts + gtot
    gemm_in_count_kernel<<<mblocks + cblocks, 256, 0, stream>>>(
        x, W_in, b_in, h16, N, idx_i, counts, P, mblocks);
    alloc_starts_kernel<<<NB, 256, 0, stream>>>(counts, starts, cursor, gtot, N);
    fill48_kernel<<<(P + 255) / 256, 256, 0, stream>>>(
        idx_i, idx_j, rcut, f_ij, cursor, rec, P);
    gather_rec_kernel<<<4096, 256, 0, stream>>>(
        rec, W_f, b_f, h16, starts, counts, agg, N);
    gemm_out_kernel<<<mblocks, 256, 0, stream>>>(agg, W_out, b_out, (float*)d_out, N);
}